// Round 3
// baseline (151.774 us; speedup 1.0000x reference)
//
#include <hip/hip_runtime.h>
#include <hip/hip_bf16.h>

#define N 8192
#define D 512

typedef __attribute__((ext_vector_type(8))) short short8;
typedef __attribute__((ext_vector_type(4))) float f32x4;

__device__ __forceinline__ float block_reduce_256(float v, float* red) {
    #pragma unroll
    for (int o = 1; o < 64; o <<= 1) v += __shfl_xor(v, o, 64);
    int w = threadIdx.x >> 6;
    if ((threadIdx.x & 63) == 0) red[w] = v;
    __syncthreads();
    float tot = red[0] + red[1] + red[2] + red[3];
    __syncthreads();
    return tot;
}

// Kernel 1: feature = row_normalize((qf-gf)^2)  [f32 to out, bf16 to ws], sq = rowsum(feature^2)
__global__ void feature_kernel(const float* __restrict__ qf, const float* __restrict__ gf,
                               float* __restrict__ feat, __hip_bfloat16* __restrict__ featb,
                               float* __restrict__ sq) {
    __shared__ float red[4];
    int row = blockIdx.x, t = threadIdx.x;
    const float2* q2 = (const float2*)(qf + (size_t)row * D);
    const float2* g2 = (const float2*)(gf + (size_t)row * D);
    float2 qv = q2[t], gv = g2[t];
    float a = qv.x - gv.x, b = qv.y - gv.y;
    float va = a * a, vb = b * b;
    float rs = block_reduce_256(va + vb, red);
    float inv = (rs == 0.0f) ? 0.0f : 1.0f / rs;
    float fa = va * inv, fb = vb * inv;
    ((float2*)(feat + (size_t)row * D))[t] = make_float2(fa, fb);
    __hip_bfloat162 h;
    h.x = __float2bfloat16(fa);
    h.y = __float2bfloat16(fb);
    ((__hip_bfloat162*)(featb + (size_t)row * D))[t] = h;
    float tot = block_reduce_256(fa * fa + fb * fb, red);
    if (t == 0) sq[row] = tot;
}

// Kernel 2: partial column sums of feature (64 blocks x 128 rows each)
__global__ void colsum_partial_kernel(const float* __restrict__ feat, float* __restrict__ partial) {
    int b = blockIdx.x, t = threadIdx.x;
    const float* fp = feat + (size_t)b * 128 * D;
    float a0 = 0.f, a1 = 0.f;
    for (int r = 0; r < 128; ++r) {
        a0 += fp[r * D + t];
        a1 += fp[r * D + t + 256];
    }
    partial[b * D + t] = a0;
    partial[b * D + t + 256] = a1;
}

// Kernel 3: finalize colsum c[512] and S = sum(sq)
__global__ void finalize_kernel(const float* __restrict__ partial, const float* __restrict__ sq,
                                float* __restrict__ cvec, float* __restrict__ Sval) {
    __shared__ float red[4];
    int t = threadIdx.x;
    if (blockIdx.x == 0) {
        float a0 = 0.f, a1 = 0.f;
        for (int b = 0; b < 64; ++b) {
            a0 += partial[b * D + t];
            a1 += partial[b * D + t + 256];
        }
        cvec[t] = a0;
        cvec[t + 256] = a1;
    } else {
        float s = 0.f;
        for (int k = 0; k < N / 256; ++k) s += sq[t + 256 * k];
        float tot = block_reduce_256(s, red);
        if (t == 0) Sval[0] = tot;
    }
}

// Kernel 4: rowinv_i = 1 / (N*sq_i + S - 2*dot(f_i, c) + 1)
__global__ void rowinv_kernel(const float* __restrict__ feat, const float* __restrict__ sq,
                              const float* __restrict__ cvec, const float* __restrict__ Sval,
                              float* __restrict__ rowinv) {
    __shared__ float red[4];
    int row = blockIdx.x, t = threadIdx.x;
    float2 f = ((const float2*)(feat + (size_t)row * D))[t];
    float2 c = ((const float2*)cvec)[t];
    float dot = block_reduce_256(f.x * c.x + f.y * c.y, red);
    if (t == 0) {
        float rs = (float)N * sq[row] + Sval[0] - 2.0f * dot + 1.0f;
        rowinv[row] = (rs == 0.0f) ? 0.0f : 1.0f / rs;
    }
}

// Kernel 5: adj[i][j] = (sq_i + sq_j - 2*(f@f^T)[i][j] + (i==j)) * rowinv_i
// 128x128 tile, BK=32, 4 waves (2x2 of 64x64), mfma_f32_16x16x32_bf16.
// REG-STAGING (global_load_dwordx4 -> ds_write_b128): all staging dependences
// are explicit VGPR/LDS deps -> no reliance on implicit vmcnt drain at barriers
// (the round-1 global_load_lds version raced under graph replay).
// LDS XOR swizzle on 16B columns, s(r) = (r>>1)&3, applied identically on the
// ds_write address and the ds_read address (same involution both sides).
__global__ __launch_bounds__(256, 2) void adj_gemm_kernel(const __hip_bfloat16* __restrict__ featb,
                                                          const float* __restrict__ sq,
                                                          const float* __restrict__ rowinv,
                                                          float* __restrict__ out) {
    __shared__ __align__(16) char lds[16384];  // A tile [128][32] bf16, B tile [128][32] bf16
    int wg = blockIdx.x;
    int swz = (wg & 7) * 512 + (wg >> 3);  // XCD-aware swizzle (4096 % 8 == 0, bijective)
    int bx = swz & 63, by = swz >> 6;
    int rowBase = by * 128, colBase = bx * 128;
    int t = threadIdx.x, lane = t & 63, w = t >> 6;
    int wr = w >> 1, wc = w & 1;

    f32x4 acc[4][4];
    #pragma unroll
    for (int m = 0; m < 4; ++m)
        #pragma unroll
        for (int n = 0; n < 4; ++n) acc[m][n] = (f32x4){0.f, 0.f, 0.f, 0.f};

    // staging: thread t handles rows r0 = t>>2 and r0+64, 16B column cc = t&3.
    // s(r0) == s(r0+64), so both chunks share the swizzled column.
    int r0 = t >> 2, cc = t & 3;
    int s0 = (r0 >> 1) & 3;
    int woff = r0 * 64 + ((cc ^ s0) * 16);  // byte offset in a [128][64B] tile
    const __hip_bfloat16* gA0 = featb + (size_t)(rowBase + r0) * D + cc * 8;
    const __hip_bfloat16* gB0 = featb + (size_t)(colBase + r0) * D + cc * 8;
    char* ldsA = lds;
    char* ldsB = lds + 8192;

    for (int ks = 0; ks < D / 32; ++ks) {
        int k0 = ks * 32;
        short8 vA0 = *(const short8*)(gA0 + k0);
        short8 vA1 = *(const short8*)(gA0 + 64 * D + k0);
        short8 vB0 = *(const short8*)(gB0 + k0);
        short8 vB1 = *(const short8*)(gB0 + 64 * D + k0);
        *(short8*)(ldsA + woff)        = vA0;
        *(short8*)(ldsA + woff + 4096) = vA1;
        *(short8*)(ldsB + woff)        = vB0;
        *(short8*)(ldsB + woff + 4096) = vB1;
        __syncthreads();

        short8 afrag[4], bfrag[4];
        #pragma unroll
        for (int m = 0; m < 4; ++m) {
            int r = wr * 64 + m * 16 + (lane & 15);
            int c16 = (lane >> 4) ^ ((r >> 1) & 3);
            afrag[m] = *(const short8*)(ldsA + r * 64 + c16 * 16);
        }
        #pragma unroll
        for (int n = 0; n < 4; ++n) {
            int r = wc * 64 + n * 16 + (lane & 15);
            int c16 = (lane >> 4) ^ ((r >> 1) & 3);
            bfrag[n] = *(const short8*)(ldsB + r * 64 + c16 * 16);
        }
        #pragma unroll
        for (int m = 0; m < 4; ++m)
            #pragma unroll
            for (int n = 0; n < 4; ++n)
                acc[m][n] = __builtin_amdgcn_mfma_f32_16x16x32_bf16(afrag[m], bfrag[n], acc[m][n], 0, 0, 0);
        __syncthreads();
    }

    // epilogue: C/D layout col=lane&15, row=(lane>>4)*4+reg
    float sqj[4];
    int jcol[4];
    #pragma unroll
    for (int n = 0; n < 4; ++n) {
        jcol[n] = colBase + wc * 64 + n * 16 + (lane & 15);
        sqj[n] = sq[jcol[n]];
    }
    #pragma unroll
    for (int m = 0; m < 4; ++m) {
        int ibase = rowBase + wr * 64 + m * 16 + ((lane >> 4) << 2);
        #pragma unroll
        for (int r = 0; r < 4; ++r) {
            int i = ibase + r;
            float si = sq[i], ri = rowinv[i];
            size_t rowoff = (size_t)i * N;
            #pragma unroll
            for (int n = 0; n < 4; ++n) {
                float pre = si + sqj[n] - 2.0f * acc[m][n][r] + (i == jcol[n] ? 1.0f : 0.0f);
                out[rowoff + jcol[n]] = pre * ri;
            }
        }
    }
}

extern "C" void kernel_launch(void* const* d_in, const int* in_sizes, int n_in,
                              void* d_out, int out_size, void* d_ws, size_t ws_size,
                              hipStream_t stream) {
    const float* qf = (const float*)d_in[0];
    const float* gf = (const float*)d_in[1];
    float* out = (float*)d_out;
    float* feat = out + (size_t)N * N;  // feature output region

    // ws layout (~8.6 MB total)
    char* wsb = (char*)d_ws;
    __hip_bfloat16* featb = (__hip_bfloat16*)wsb;                          // 8 MB bf16 feature
    float* sq      = (float*)(wsb + 8388608);                              // 32 KB
    float* partial = (float*)(wsb + 8388608 + 32768);                      // 128 KB
    float* cvec    = (float*)(wsb + 8388608 + 32768 + 131072);             // 2 KB
    float* Sval    = (float*)(wsb + 8388608 + 32768 + 131072 + 2048);      // 4 B (+pad)
    float* rowinv  = (float*)(wsb + 8388608 + 32768 + 131072 + 2048 + 64); // 32 KB

    feature_kernel<<<N, 256, 0, stream>>>(qf, gf, feat, featb, sq);
    colsum_partial_kernel<<<64, 256, 0, stream>>>(feat, partial);
    finalize_kernel<<<2, 256, 0, stream>>>(partial, sq, cvec, Sval);
    rowinv_kernel<<<N, 256, 0, stream>>>(feat, sq, cvec, Sval, rowinv);
    adj_gemm_kernel<<<4096, 256, 0, stream>>>(featb, sq, rowinv, out);
}

// Round 5
// 124.809 us; speedup vs baseline: 1.2161x; 1.2161x over previous
//
#include <hip/hip_runtime.h>
#include <hip/hip_bf16.h>

#define N 8192
#define D 512

typedef __attribute__((ext_vector_type(8))) short short8;
typedef __attribute__((ext_vector_type(4))) float f32x4;

__device__ __forceinline__ float block_reduce_256(float v, float* red) {
    #pragma unroll
    for (int o = 1; o < 64; o <<= 1) v += __shfl_xor(v, o, 64);
    int w = threadIdx.x >> 6;
    if ((threadIdx.x & 63) == 0) red[w] = v;
    __syncthreads();
    float tot = red[0] + red[1] + red[2] + red[3];
    __syncthreads();
    return tot;
}

// Kernel 1: feature = row_normalize((qf-gf)^2)  [f32 to out, bf16 to ws], sq = rowsum(feature^2)
__global__ void feature_kernel(const float* __restrict__ qf, const float* __restrict__ gf,
                               float* __restrict__ feat, __hip_bfloat16* __restrict__ featb,
                               float* __restrict__ sq) {
    __shared__ float red[4];
    int row = blockIdx.x, t = threadIdx.x;
    const float2* q2 = (const float2*)(qf + (size_t)row * D);
    const float2* g2 = (const float2*)(gf + (size_t)row * D);
    float2 qv = q2[t], gv = g2[t];
    float a = qv.x - gv.x, b = qv.y - gv.y;
    float va = a * a, vb = b * b;
    float rs = block_reduce_256(va + vb, red);
    float inv = (rs == 0.0f) ? 0.0f : 1.0f / rs;
    float fa = va * inv, fb = vb * inv;
    ((float2*)(feat + (size_t)row * D))[t] = make_float2(fa, fb);
    __hip_bfloat162 h;
    h.x = __float2bfloat16(fa);
    h.y = __float2bfloat16(fb);
    ((__hip_bfloat162*)(featb + (size_t)row * D))[t] = h;
    float tot = block_reduce_256(fa * fa + fb * fb, red);
    if (t == 0) sq[row] = tot;
}

// Kernel 2: partial column sums of feature (64 blocks x 128 rows each)
__global__ void colsum_partial_kernel(const float* __restrict__ feat, float* __restrict__ partial) {
    int b = blockIdx.x, t = threadIdx.x;
    const float* fp = feat + (size_t)b * 128 * D;
    float a0 = 0.f, a1 = 0.f;
    for (int r = 0; r < 128; ++r) {
        a0 += fp[r * D + t];
        a1 += fp[r * D + t + 256];
    }
    partial[b * D + t] = a0;
    partial[b * D + t + 256] = a1;
}

// Kernel 3: finalize colsum c[512] and S = sum(sq)
__global__ void finalize_kernel(const float* __restrict__ partial, const float* __restrict__ sq,
                                float* __restrict__ cvec, float* __restrict__ Sval) {
    __shared__ float red[4];
    int t = threadIdx.x;
    if (blockIdx.x == 0) {
        float a0 = 0.f, a1 = 0.f;
        for (int b = 0; b < 64; ++b) {
            a0 += partial[b * D + t];
            a1 += partial[b * D + t + 256];
        }
        cvec[t] = a0;
        cvec[t + 256] = a1;
    } else {
        float s = 0.f;
        for (int k = 0; k < N / 256; ++k) s += sq[t + 256 * k];
        float tot = block_reduce_256(s, red);
        if (t == 0) Sval[0] = tot;
    }
}

// Kernel 4: rowinv_i = 1 / (N*sq_i + S - 2*dot(f_i, c) + 1)
__global__ void rowinv_kernel(const float* __restrict__ feat, const float* __restrict__ sq,
                              const float* __restrict__ cvec, const float* __restrict__ Sval,
                              float* __restrict__ rowinv) {
    __shared__ float red[4];
    int row = blockIdx.x, t = threadIdx.x;
    float2 f = ((const float2*)(feat + (size_t)row * D))[t];
    float2 c = ((const float2*)cvec)[t];
    float dot = block_reduce_256(f.x * c.x + f.y * c.y, red);
    if (t == 0) {
        float rs = (float)N * sq[row] + Sval[0] - 2.0f * dot + 1.0f;
        rowinv[row] = (rs == 0.0f) ? 0.0f : 1.0f / rs;
    }
}

// Kernel 5 (symmetric): adj_pre is symmetric, so compute only tiles by<=bx
// (2080 of 4096) and emit both out[i][j]=pre*rowinv[i] (direct) and
// out[j][i]=pre*rowinv[j] (via per-wave LDS transpose, stride-72 f32 pad).
// K-loop: BK=64, LDS double-buffer, reg-staged (explicit deps only),
// ONE barrier per K-step, next-tile global loads issued before MFMA (T14).
// LDS swizzle on 16B chunks: c' = c ^ (row&7), same involution both sides.
// NOTE: no LDS pointer arrays (addrspacecast static-init is unsupported on
// gfx950) -- double-buffer pointers are computed from `cur` arithmetically.
__global__ __launch_bounds__(256, 2) void adj_gemm_sym_kernel(const __hip_bfloat16* __restrict__ featb,
                                                              const float* __restrict__ sq,
                                                              const float* __restrict__ rowinv,
                                                              float* __restrict__ out) {
    __shared__ __align__(16) char lds[73728];  // stage: 4x16KB (A0,A1,B0,B1); epi: 4x18432B per-wave T
    int wg = blockIdx.x;
    int id = (wg & 7) * 260 + (wg >> 3);  // XCD swizzle, 2080 = 8*260 (bijective)
    // triangular decode: by = r with o(r) <= id < o(r+1), o(r) = r*(129-r)/2
    int r = (int)((129.0f - sqrtf(16641.0f - 8.0f * (float)id)) * 0.5f);
    if (r > 63) r = 63;
    while (r > 0 && (r * (129 - r)) / 2 > id) --r;
    while (((r + 1) * (128 - r)) / 2 <= id) ++r;
    int by = r;
    int bx = r + (id - (r * (129 - r)) / 2);
    int rowBase = by * 128, colBase = bx * 128;

    int t = threadIdx.x, lane = t & 63, w = t >> 6;
    int wr = w >> 1, wc = w & 1, g = lane >> 4;

    f32x4 acc[4][4];
    #pragma unroll
    for (int m = 0; m < 4; ++m)
        #pragma unroll
        for (int n = 0; n < 4; ++n) acc[m][n] = (f32x4){0.f, 0.f, 0.f, 0.f};

    // staging: thread t -> rows srow+32q (q=0..3), 16B chunk schunk of a [128][128B] tile
    int srow = t >> 3, schunk = t & 7;
    const __hip_bfloat16* gA = featb + (size_t)(rowBase + srow) * D + schunk * 8;
    const __hip_bfloat16* gB = featb + (size_t)(colBase + srow) * D + schunk * 8;
    int wo0 = srow * 128 + ((schunk ^ (srow & 7)) * 16);  // (srow+32q)&7 == srow&7

    // fragment read offsets: row = w*64 + m*16 + (lane&15); chunk = kk*4+g, swz ^ (lane&7)
    int arow = wr * 64 + (lane & 15);
    int brow = wc * 64 + (lane & 15);
    int swzc = lane & 7;
    int ca0 = ((g) ^ swzc) * 16, ca1 = ((4 + g) ^ swzc) * 16;

    short8 ra[4], rb[4];
    #pragma unroll
    for (int q = 0; q < 4; ++q) {
        ra[q] = *(const short8*)(gA + (size_t)q * 32 * D);
        rb[q] = *(const short8*)(gB + (size_t)q * 32 * D);
    }
    #pragma unroll
    for (int q = 0; q < 4; ++q) {
        *(short8*)(lds + wo0 + q * 4096) = ra[q];
        *(short8*)(lds + 32768 + wo0 + q * 4096) = rb[q];
    }
    __syncthreads();

    int cur = 0;
    for (int ks = 0; ks < 8; ++ks) {
        if (ks < 7) {
            int k0 = (ks + 1) * 64;
            #pragma unroll
            for (int q = 0; q < 4; ++q) {
                ra[q] = *(const short8*)(gA + (size_t)q * 32 * D + k0);
                rb[q] = *(const short8*)(gB + (size_t)q * 32 * D + k0);
            }
        }
        short8 af[4][2], bf[4][2];
        const char* pA = lds + (cur << 14);
        const char* pB = lds + 32768 + (cur << 14);
        #pragma unroll
        for (int m = 0; m < 4; ++m) {
            af[m][0] = *(const short8*)(pA + (arow + 16 * m) * 128 + ca0);
            af[m][1] = *(const short8*)(pA + (arow + 16 * m) * 128 + ca1);
            bf[m][0] = *(const short8*)(pB + (brow + 16 * m) * 128 + ca0);
            bf[m][1] = *(const short8*)(pB + (brow + 16 * m) * 128 + ca1);
        }
        #pragma unroll
        for (int m = 0; m < 4; ++m)
            #pragma unroll
            for (int n = 0; n < 4; ++n) {
                acc[m][n] = __builtin_amdgcn_mfma_f32_16x16x32_bf16(af[m][0], bf[n][0], acc[m][n], 0, 0, 0);
                acc[m][n] = __builtin_amdgcn_mfma_f32_16x16x32_bf16(af[m][1], bf[n][1], acc[m][n], 0, 0, 0);
            }
        if (ks < 7) {
            char* wA = lds + ((cur ^ 1) << 14);
            char* wB = lds + 32768 + ((cur ^ 1) << 14);
            #pragma unroll
            for (int q = 0; q < 4; ++q) {
                *(short8*)(wA + wo0 + q * 4096) = ra[q];
                *(short8*)(wB + wo0 + q * 4096) = rb[q];
            }
        }
        __syncthreads();
        cur ^= 1;
    }

    // epilogue: C/D layout col=lane&15, row=g*4+reg. Direct tile + (off-diag) LDS transpose.
    float* T = (float*)(lds + w * 18432);  // [64 jj][72 ii] f32, wave-private
    float sqj[4];
    int jcol[4];
    #pragma unroll
    for (int n = 0; n < 4; ++n) {
        jcol[n] = colBase + wc * 64 + n * 16 + (lane & 15);
        sqj[n] = sq[jcol[n]];
    }
    int offdiag = (by != bx);
    #pragma unroll
    for (int m = 0; m < 4; ++m) {
        int ibase = rowBase + wr * 64 + m * 16 + g * 4;
        #pragma unroll
        for (int rI = 0; rI < 4; ++rI) {
            int i = ibase + rI;
            float si = sq[i], ri = rowinv[i];
            size_t ro = (size_t)i * N;
            #pragma unroll
            for (int n = 0; n < 4; ++n) {
                float pre = si + sqj[n] - 2.0f * acc[m][n][rI] + (i == jcol[n] ? 1.0f : 0.0f);
                out[ro + jcol[n]] = pre * ri;
                if (offdiag) {
                    int ii = m * 16 + g * 4 + rI;
                    int jj = n * 16 + (lane & 15);
                    T[jj * 72 + ii] = pre;
                }
            }
        }
    }
    if (offdiag) {
        __syncthreads();
        #pragma unroll
        for (int it = 0; it < 16; ++it) {
            int jj = it * 4 + g;
            int ii0 = (lane & 15) * 4;
            f32x4 v = *(const f32x4*)&T[jj * 72 + ii0];
            int j = colBase + wc * 64 + jj;
            float rj = rowinv[j];
            v *= rj;
            *(f32x4*)&out[(size_t)j * N + rowBase + wr * 64 + ii0] = v;
        }
    }
}

extern "C" void kernel_launch(void* const* d_in, const int* in_sizes, int n_in,
                              void* d_out, int out_size, void* d_ws, size_t ws_size,
                              hipStream_t stream) {
    const float* qf = (const float*)d_in[0];
    const float* gf = (const float*)d_in[1];
    float* out = (float*)d_out;
    float* feat = out + (size_t)N * N;  // feature output region

    // ws layout (~8.6 MB total)
    char* wsb = (char*)d_ws;
    __hip_bfloat16* featb = (__hip_bfloat16*)wsb;                          // 8 MB bf16 feature
    float* sq      = (float*)(wsb + 8388608);                              // 32 KB
    float* partial = (float*)(wsb + 8388608 + 32768);                      // 128 KB
    float* cvec    = (float*)(wsb + 8388608 + 32768 + 131072);             // 2 KB
    float* Sval    = (float*)(wsb + 8388608 + 32768 + 131072 + 2048);      // 4 B (+pad)
    float* rowinv  = (float*)(wsb + 8388608 + 32768 + 131072 + 2048 + 64); // 32 KB

    feature_kernel<<<N, 256, 0, stream>>>(qf, gf, feat, featb, sq);
    colsum_partial_kernel<<<64, 256, 0, stream>>>(feat, partial);
    finalize_kernel<<<2, 256, 0, stream>>>(partial, sq, cvec, Sval);
    rowinv_kernel<<<N, 256, 0, stream>>>(feat, sq, cvec, Sval, rowinv);
    adj_gemm_sym_kernel<<<2080, 256, 0, stream>>>(featb, sq, rowinv, out);
}